// Round 3
// baseline (111.599 us; speedup 1.0000x reference)
//
#include <hip/hip_runtime.h>

typedef float f32x16 __attribute__((ext_vector_type(16)));

#define HW    4096
#define TPB   256
#define GRID  512   // 512 blocks x 2 tiles x 128 positions = 131072

// ws layout: [0,32768) fp8 codebook fragments (4096 u64 slots, exact LDS image)
//            [32768,34816) ecb biases (512 f32):  128 + 256*||e_k||^2
//            [34816] loss accumulator (f32), [34820] completion counter (u32)

__global__ __launch_bounds__(256)
void vq_prep(const float* __restrict__ cb,
             unsigned long long* __restrict__ wcb,
             float* __restrict__ wecb,
             float* __restrict__ wloss,
             unsigned* __restrict__ wcnt)
{
    const int t = threadIdx.x, bk = blockIdx.x;
    #pragma unroll
    for (int j = 0; j < 4; ++j) {
        int slot  = bk * 1024 + t + 256 * j;     // ((chunk*4+s)*64+lane)
        int lane  = slot & 63;
        int s     = (slot >> 6) & 3;
        int chunk = slot >> 8;
        int code  = chunk * 32 + (lane & 31);
        int c0    = s * 16 + (lane >> 5) * 8;
        const float4* p = (const float4*)(cb + code * 64 + c0);
        float4 a0 = p[0], a1 = p[1];
        int w0, w1;
        w0 = __builtin_amdgcn_cvt_pk_fp8_f32(-512.f * a0.x, -512.f * a0.y, 0,  false);
        w0 = __builtin_amdgcn_cvt_pk_fp8_f32(-512.f * a0.z, -512.f * a0.w, w0, true);
        w1 = __builtin_amdgcn_cvt_pk_fp8_f32(-512.f * a1.x, -512.f * a1.y, 0,  false);
        w1 = __builtin_amdgcn_cvt_pk_fp8_f32(-512.f * a1.z, -512.f * a1.w, w1, true);
        wcb[slot] = ((unsigned long long)(unsigned)w1 << 32) | (unsigned long long)(unsigned)w0;
    }
    if (t < 128) {
        int code = bk * 128 + t;
        const float4* p = (const float4*)(cb + code * 64);
        float ssum = 0.f;
        #pragma unroll
        for (int q4 = 0; q4 < 16; ++q4) {
            float4 a = p[q4];
            ssum = fmaf(a.x, a.x, ssum); ssum = fmaf(a.y, a.y, ssum);
            ssum = fmaf(a.z, a.z, ssum); ssum = fmaf(a.w, a.w, ssum);
        }
        wecb[code] = 128.f + 256.f * ssum;
    }
    if (bk == 0 && t == 0) { *wloss = 0.f; *wcnt = 0u; }
}

// per-tile compute: MFMA 32x32x16 fp8 + u32 running argmin + cross-lane reduce
#define COMPUTE_TILE(BUF)                                                        \
    {                                                                            \
        long az0 = (long)zB[BUF][w][0][l];                                       \
        long az1 = (long)zB[BUF][w][1][l];                                       \
        long az2 = (long)zB[BUF][w][2][l];                                       \
        long az3 = (long)zB[BUF][w][3][l];                                       \
        unsigned urun[16];                                                       \
        _Pragma("unroll")                                                        \
        for (int i = 0; i < 16; ++i) urun[i] = 0xFFFFFFFFu;                      \
        for (int chunk = 0; chunk < 16; ++chunk) {                               \
            const unsigned long long* cbp = &shCB[chunk * 256 + l];              \
            long b0 = (long)cbp[0];   long b1 = (long)cbp[64];                   \
            long b2 = (long)cbp[128]; long b3 = (long)cbp[192];                  \
            float bias = ecb[chunk * 32 + (l & 31)];                             \
            f32x16 acc;                                                          \
            _Pragma("unroll")                                                    \
            for (int i = 0; i < 16; ++i) acc[i] = bias;                          \
            acc = __builtin_amdgcn_mfma_f32_32x32x16_fp8_fp8(az0, b0, acc, 0,0,0); \
            acc = __builtin_amdgcn_mfma_f32_32x32x16_fp8_fp8(az1, b1, acc, 0,0,0); \
            acc = __builtin_amdgcn_mfma_f32_32x32x16_fp8_fp8(az2, b2, acc, 0,0,0); \
            acc = __builtin_amdgcn_mfma_f32_32x32x16_fp8_fp8(az3, b3, acc, 0,0,0); \
            unsigned kor = (unsigned)(chunk * 32 + (l & 31));                    \
            _Pragma("unroll")                                                    \
            for (int i = 0; i < 16; ++i) {                                       \
                unsigned u = (__float_as_uint(acc[i]) & 0xFFFFFE00u) | kor;      \
                urun[i] = (u < urun[i]) ? u : urun[i];                           \
            }                                                                    \
        }                                                                        \
        _Pragma("unroll")                                                        \
        for (int i = 0; i < 16; ++i) {                                           \
            unsigned u = urun[i];                                                \
            _Pragma("unroll")                                                    \
            for (int m = 1; m <= 16; m <<= 1) {                                  \
                unsigned o = __shfl_xor(u, m, 64);                               \
                u = (o < u) ? o : u;                                             \
            }                                                                    \
            urun[i] = u;                                                         \
        }                                                                        \
        if ((l & 31) == 0) {                                                     \
            int hh = l >> 5;                                                     \
            _Pragma("unroll")                                                    \
            for (int i = 0; i < 16; ++i)                                         \
                minu[BUF][32 * w + (i & 3) + 8 * (i >> 2) + 4 * hh] = urun[i];   \
        }                                                                        \
    }

#define CVT_TILE(BUF, F, ZSQ)                                                    \
    _Pragma("unroll")                                                            \
    for (int jj = 0; jj < 4; ++jj) {                                             \
        int w0, w1;                                                              \
        _Pragma("unroll")                                                        \
        for (int i = 0; i < 8; ++i) ZSQ = fmaf(F[jj][i], F[jj][i], ZSQ);         \
        w0 = __builtin_amdgcn_cvt_pk_fp8_f32(F[jj][0], F[jj][1], 0,  false);     \
        w0 = __builtin_amdgcn_cvt_pk_fp8_f32(F[jj][2], F[jj][3], w0, true);      \
        w1 = __builtin_amdgcn_cvt_pk_fp8_f32(F[jj][4], F[jj][5], 0,  false);     \
        w1 = __builtin_amdgcn_cvt_pk_fp8_f32(F[jj][6], F[jj][7], w1, true);      \
        zB[BUF][p >> 5][2 * half + (jj >> 1)][(p & 31) + 32 * (jj & 1)] =        \
            ((unsigned long long)(unsigned)w1 << 32) | (unsigned long long)(unsigned)w0; \
    }

#define STORE_TILE(BUF, XOFF, ZSQ)                                              \
    {                                                                            \
        unsigned u = minu[BUF][p];                                               \
        int k = (int)(u & 511u);                                                 \
        float sprime = __uint_as_float(u & 0xFFFFFE00u);                         \
        lossacc += ZSQ + (half == 0 ? (sprime - 128.f) * (1.f / 256.f) : 0.f);   \
        float* ob = out + (size_t)(b * 64 + 32 * half) * HW + hw0 + p + XOFF;    \
        _Pragma("unroll")                                                        \
        for (int jj = 0; jj < 4; ++jj) {                                         \
            unsigned long long q =                                               \
                shCB[((k >> 5) * 4 + 2 * half + (jj >> 1)) * 64 + (k & 31) + 32 * (jj & 1)]; \
            int qlo = (int)(unsigned)(q & 0xFFFFFFFFull);                        \
            int qhi = (int)(unsigned)(q >> 32);                                  \
            float v[8];                                                          \
            v[0] = __builtin_amdgcn_cvt_f32_fp8(qlo, 0);                         \
            v[1] = __builtin_amdgcn_cvt_f32_fp8(qlo, 1);                         \
            v[2] = __builtin_amdgcn_cvt_f32_fp8(qlo, 2);                         \
            v[3] = __builtin_amdgcn_cvt_f32_fp8(qlo, 3);                         \
            v[4] = __builtin_amdgcn_cvt_f32_fp8(qhi, 0);                         \
            v[5] = __builtin_amdgcn_cvt_f32_fp8(qhi, 1);                         \
            v[6] = __builtin_amdgcn_cvt_f32_fp8(qhi, 2);                         \
            v[7] = __builtin_amdgcn_cvt_f32_fp8(qhi, 3);                         \
            _Pragma("unroll")                                                    \
            for (int i = 0; i < 8; ++i) ob[(jj * 8 + i) * HW] = v[i] * (-1.f / 512.f); \
        }                                                                        \
    }

__global__ __launch_bounds__(TPB, 2)
void vq_main(const float* __restrict__ x,
             const unsigned long long* __restrict__ wcb,
             float* __restrict__ out,
             float* __restrict__ loss_out,
             float* __restrict__ wloss,
             unsigned* __restrict__ wcnt)
{
    __shared__ unsigned long long shCB[4608];        // [0,4096) frags, [4096,4608) ecb
    __shared__ unsigned long long zB[2][4][4][64];   // 16 KB
    __shared__ unsigned minu[2][128];
    __shared__ float red[4];

    const int t    = threadIdx.x;
    const int l    = t & 63;
    const int w    = t >> 6;
    const int p    = t & 127;        // position within tile
    const int half = t >> 7;         // channel half (0: c<32, 1: c>=32)
    const int n0   = blockIdx.x * 256;
    const int b    = n0 >> 12;
    const int hw0  = n0 & (HW - 1);

    // issue codebook+bias L2->LDS copy (34 x 1KB, exact image from prep)
    {
        const char* gsrc = (const char*)wcb;
        for (int i = w; i < 34; i += 4) {
            const char* gp = gsrc + i * 1024 + l * 16;
            char* lp = (char*)shCB + i * 1024;
            __builtin_amdgcn_global_load_lds(
                (const __attribute__((address_space(1))) void*)gp,
                (__attribute__((address_space(3))) void*)lp, 16, 0, 0);
        }
    }
    const float* ecb = (const float*)&shCB[4096];

    const float* xb0 = x + (size_t)(b * 64 + 32 * half) * HW + hw0 + p;

    // ---- tile0: load + convert ----
    float zsq0 = 0.f;
    {
        float f0[4][8];
        #pragma unroll
        for (int jj = 0; jj < 4; ++jj)
            #pragma unroll
            for (int i = 0; i < 8; ++i) f0[jj][i] = xb0[(jj * 8 + i) * HW];
        CVT_TILE(0, f0, zsq0)
    }
    __syncthreads();   // codebook + zB[0] ready

    // ---- issue tile1 loads early (hidden under tile0 compute) ----
    float f1[4][8];
    {
        const float* xb1 = xb0 + 128;
        #pragma unroll
        for (int jj = 0; jj < 4; ++jj)
            #pragma unroll
            for (int i = 0; i < 8; ++i) f1[jj][i] = xb1[(jj * 8 + i) * HW];
    }

    float lossacc = 0.f;
    COMPUTE_TILE(0)

    float zsq1 = 0.f;
    CVT_TILE(1, f1, zsq1)
    __syncthreads();   // minu[0] + zB[1] ready

    STORE_TILE(0, 0, zsq0)     // stores overlap tile1 compute
    COMPUTE_TILE(1)
    __syncthreads();   // minu[1] ready

    STORE_TILE(1, 128, zsq1)

    // ---- loss reduction: block -> ws atomic -> last block writes output ----
    #pragma unroll
    for (int m = 1; m < 64; m <<= 1) lossacc += __shfl_xor(lossacc, m, 64);
    if (l == 0) red[w] = lossacc;
    __syncthreads();
    if (t == 0) {
        float partial = red[0] + red[1] + red[2] + red[3];
        atomicAdd(wloss, partial);
        __threadfence();
        unsigned old = atomicAdd(wcnt, 1u);
        if (old == (unsigned)(GRID - 1)) {
            float tot = atomicAdd(wloss, 0.0f);   // coherent read
            loss_out[0] = tot * (1.25f / 8388608.0f);
        }
    }
}

extern "C" void kernel_launch(void* const* d_in, const int* in_sizes, int n_in,
                              void* d_out, int out_size, void* d_ws, size_t ws_size,
                              hipStream_t stream) {
    const float* x  = (const float*)d_in[0];
    const float* cb = (const float*)d_in[1];
    float* out  = (float*)d_out;
    float* loss = out + (out_size - 1);

    unsigned long long* wcb = (unsigned long long*)d_ws;
    float*    wecb  = (float*)((char*)d_ws + 32768);
    float*    wloss = (float*)((char*)d_ws + 34816);
    unsigned* wcnt  = (unsigned*)((char*)d_ws + 34820);

    vq_prep<<<dim3(4), dim3(256), 0, stream>>>(cb, wcb, wecb, wloss, wcnt);
    vq_main<<<dim3(GRID), dim3(TPB), 0, stream>>>(x, wcb, out, loss, wloss, wcnt);
}